// Round 14
// baseline (34.958 us; speedup 1.0000x reference)
//
#include <hip/hip_runtime.h>

// R14: R13 + non-temporal x loads (protect L2 from the zero-reuse x stream,
//   so the 256-block-shared weff/W2 actually get L2 hits) + GEMM3 M-split
//   across wv_n + nt out-stores. Structure otherwise frozen from R13.

typedef __attribute__((ext_vector_type(8))) short bf16x8;
typedef __attribute__((ext_vector_type(4))) float f32x4;

#define KP1 832
#define NPB 128     // weff rows padded (uniform B staging)
#define NP  112
#define K2P 128
#define BM  128
#define NT  512

#define W2T_OFF (NPB * KP1)             // 106496
#define W3T_OFF (W2T_OFF + NP * K2P)    // 120832

#define SBAR0 __builtin_amdgcn_sched_barrier(0)
#define BAR   __builtin_amdgcn_s_barrier()
#define WAITV(N) asm volatile("s_waitcnt vmcnt(" #N ")" ::: "memory")
#define WAITL    asm volatile("s_waitcnt lgkmcnt(0)" ::: "memory")

__device__ __forceinline__ unsigned short f2bf(float f) {
    unsigned int u = __float_as_uint(f);
    u += 0x7FFFu + ((u >> 16) & 1u);    // RNE
    return (unsigned short)(u >> 16);
}

__device__ __forceinline__ unsigned int pkbf(float a, float b) {
    unsigned int r;
    asm("v_cvt_pk_bf16_f32 %0, %1, %2" : "=v"(r) : "v"(a), "v"(b));
    return r;
}

__device__ __forceinline__ void gload_lds16(const void* g, void* l) {
    __builtin_amdgcn_global_load_lds(
        (const __attribute__((address_space(1))) unsigned int*)g,
        (__attribute__((address_space(3))) unsigned int*)l, 16, 0, 0);
}

// ---------------- Kernel A: weights -> bf16, transposed, padded (128-row weff)
__global__ void build_weights(const float* __restrict__ w_conv,
                              const float* __restrict__ W1,
                              const float* __restrict__ W2,
                              const float* __restrict__ W3,
                              unsigned short* __restrict__ ws) {
    const int idx = blockIdx.x * 256 + threadIdx.x;
    const int WEFF_T = 32 * KP1;                 // 32 j-quads (128 rows)
    if (idx < WEFF_T) {
        const int j4 = idx / KP1, p = idx % KP1;
        const int j = j4 * 4;
        float a0 = 0.f, a1 = 0.f, a2 = 0.f, a3 = 0.f;
        if (p < 784 && j4 < 25) {
            const int y = p / 28, xx = p % 28;
#pragma unroll
            for (int ky = 0; ky < 3; ++ky) {
                const int py = y - ky;
                if (py < 0 || py >= 26) continue;
#pragma unroll
                for (int kx = 0; kx < 3; ++kx) {
                    const int px = xx - kx;
                    if (px < 0 || px >= 26) continue;
                    const float wc = w_conv[ky * 3 + kx];
                    const float4 w = *reinterpret_cast<const float4*>(
                        W1 + (size_t)(py * 26 + px) * 100 + j);
                    a0 = fmaf(wc, w.x, a0); a1 = fmaf(wc, w.y, a1);
                    a2 = fmaf(wc, w.z, a2); a3 = fmaf(wc, w.w, a3);
                }
            }
        }
        ws[(size_t)(j + 0) * KP1 + p] = f2bf(a0);
        ws[(size_t)(j + 1) * KP1 + p] = f2bf(a1);
        ws[(size_t)(j + 2) * KP1 + p] = f2bf(a2);
        ws[(size_t)(j + 3) * KP1 + p] = f2bf(a3);
    } else if (idx < WEFF_T + NP * K2P) {
        const int r = idx - WEFF_T;
        const int col = r / K2P, k = r % K2P;
        float v = (col < 100 && k < 100) ? W2[k * 100 + col] : 0.f;
        ws[W2T_OFF + r] = f2bf(v);
    } else if (idx < WEFF_T + NP * K2P + 16 * K2P) {
        const int r = idx - WEFF_T - NP * K2P;
        const int col = r / K2P, k = r % K2P;
        float v = (col < 10 && k < 100) ? W3[k * 10 + col] : 0.f;
        ws[W3T_OFF + r] = f2bf(v);
    }
}

// ---------------- Kernel B: fused
union SMem {
    struct {
        unsigned short xs[2][BM][72];    // 36864 B (bf16, 2-way banks)
        unsigned short bs[2][NPB][64];   // 32768 B (gload_lds, XOR-swizzled)
    } g1;                                 // 69632 B
    struct {
        unsigned short h1[BM][136];      // 34816 B
        union {
            unsigned short w2s[NP][136]; // 30464 B (dead before h2 written)
            unsigned short h2[BM][136];  // 34816 B
        } u;
    } g2;                                 // 69632 B
};

__global__ __launch_bounds__(NT, 2)
void fused(const float* __restrict__ x,
           const unsigned short* __restrict__ wst,
           const float* __restrict__ b1,
           const float* __restrict__ b2,
           const float* __restrict__ b3,
           float* __restrict__ out) {
    __shared__ SMem sm;
    const int tid  = threadIdx.x;
    const int lane = tid & 63;
    const int wv   = tid >> 6;        // 0..7
    const int wv_m = wv >> 1;         // 0..3 -> rows wv_m*32 (2 m-frags)
    const int wv_n = wv & 1;          // 0..1 -> frags wv_n*4..(+3|+2)
    const int l15  = lane & 15;
    const int lk   = lane >> 4;       // 0..3
    const int wrow = wv_m * 32;
    const int nb   = wv_n * 4;
    const size_t b0 = (size_t)blockIdx.x * BM;

    const unsigned short* weff = wst;
    const unsigned short* w2t  = wst + W2T_OFF;
    const unsigned short* w3t  = wst + W3T_OFF;

    // x staging map: idx=q*512+tid -> row=idx>>4 (xrow+q*32), chunk=idx&15
    const int xrow = tid >> 4;
    const int xch  = tid & 15;
    const float* xbase = x + (b0 + xrow) * 784 + xch * 4;

    f32x4 acc[2][4];
#pragma unroll
    for (int m = 0; m < 2; ++m)
#pragma unroll
        for (int j = 0; j < 4; ++j) acc[m][j] = (f32x4){0.f, 0.f, 0.f, 0.f};

    f32x4 xv[4];
    auto issueX = [&](int kt) {
#pragma unroll
        for (int q = 0; q < 4; ++q) {
            if (kt < 12 || xch < 4)   // stage 12: cols>=784 are pad
                xv[q] = __builtin_nontemporal_load(
                    reinterpret_cast<const f32x4*>(xbase + (size_t)q * 32 * 784 + kt * 64));
            else
                xv[q] = (f32x4){0.f, 0.f, 0.f, 0.f};
        }
    };
    auto writeX = [&](int buf) {
        char* xp = (char*)&sm.g1.xs[buf][0][0];
#pragma unroll
        for (int q = 0; q < 4; ++q) {
            const uint2 w = {pkbf(xv[q].x, xv[q].y), pkbf(xv[q].z, xv[q].w)};
            *reinterpret_cast<uint2*>(xp + (xrow + q * 32) * 144 + xch * 8) = w;
        }
    };
    auto issueB = [&](int kt, int buf) {   // 2 gloads/wave: groups wv, wv+8
#pragma unroll
        for (int q = 0; q < 2; ++q) {
            const int g  = wv + 8 * q;
            const int rg = g * 8 + (lane >> 3);
            const int ch = (lane & 7) ^ (lane >> 3);       // inverse swizzle
            gload_lds16((const char*)weff + (size_t)rg * KP1 * 2 + kt * 128 + ch * 16,
                        &sm.g1.bs[buf][g * 8][0]);
        }
    };
    auto computeStage = [&](int buf) {
        const char* xp = (const char*)&sm.g1.xs[buf][0][0];
        const char* bp = (const char*)&sm.g1.bs[buf][0][0];
#pragma unroll
        for (int kh = 0; kh < 2; ++kh) {
            bf16x8 a[2];
#pragma unroll
            for (int m = 0; m < 2; ++m)
                a[m] = *reinterpret_cast<const bf16x8*>(
                    xp + (wrow + m * 16 + l15) * 144 + kh * 64 + lk * 16);
#pragma unroll
            for (int j = 0; j < 4; ++j) {
                const int nf = nb + j;
                if (nf < 7) {
                    const int rn = nf * 16 + l15;
                    const bf16x8 b = *reinterpret_cast<const bf16x8*>(
                        bp + rn * 128 + ((kh * 64 + lk * 16) ^ ((rn & 7) << 4)));
#pragma unroll
                    for (int m = 0; m < 2; ++m)
                        acc[m][j] = __builtin_amdgcn_mfma_f32_16x16x32_bf16(
                            a[m], b, acc[m][j], 0, 0, 0);
                }
            }
        }
    };

    // ---- GEMM1 prologue
    issueX(0); SBAR0;
    issueB(0, 0); SBAR0;
    WAITV(2); SBAR0;              // x(0) landed (B(0) in flight)
    writeX(0); SBAR0;
    issueX(1); SBAR0;             // outstanding: B(0)2 + x(1)4
    WAITV(4);                     // B(0) landed
    WAITL; BAR;

    // ---- GEMM1: 13 stages; entering t: xs/bs[t&1] ready, x(t+1) in flight
#pragma unroll
    for (int t = 0; t < 13; ++t) {
        if (t < 12) { issueB(t + 1, (t + 1) & 1); SBAR0; }   // buf retired at barrier(t-1)
        computeStage(t & 1);
        if (t == 12) break;
        WAITV(2); SBAR0;          // x(t+1) landed (B(t+1) in flight)
        writeX((t + 1) & 1); SBAR0;
        if (t < 11) { issueX(t + 2); SBAR0; WAITV(4); }      // B(t+1) landed
        else        { WAITV(0); }                             // drain B(12)
        WAITL; BAR;
    }
    __syncthreads();   // all g1 reads done -> g2 alias safe

    // ---- h1 = relu(acc+b1); h1 k-pad; stage W2 -> LDS
    {
        float bias[4];
#pragma unroll
        for (int j = 0; j < 4; ++j) {
            const int c = (nb + j) * 16 + l15;
            bias[j] = (nb + j < 7 && c < 100) ? b1[c] : 0.f;
        }
#pragma unroll
        for (int j = 0; j < 4; ++j) {
            const int nf = nb + j, col = nf * 16 + l15;
            if (nf < 7 && col < 100)
#pragma unroll
                for (int m = 0; m < 2; ++m)
#pragma unroll
                    for (int q = 0; q < 4; ++q)
                        sm.g2.h1[wrow + m * 16 + lk * 4 + q][col] =
                            f2bf(fmaxf(acc[m][j][q] + bias[j], 0.f));
        }
        if (wv_n == 1) {   // zero h1 pad cols 100..127 for rows wrow..wrow+31
            for (int f = lane; f < 32 * 14; f += 64) {
                const int r = wrow + f / 14, c = 100 + (f % 14) * 2;
                *reinterpret_cast<unsigned int*>(&sm.g2.h1[r][c]) = 0u;
            }
        }
#pragma unroll
        for (int q = 0; q < 4; ++q) {   // w2s[112][136] <- w2t (1792 chunks)
            const int idx = q * NT + tid;
            if (idx < 1792) {
                const int row = idx >> 4, ch = idx & 15;
                *reinterpret_cast<bf16x8*>(&sm.g2.u.w2s[row][ch * 8]) =
                    *reinterpret_cast<const bf16x8*>(w2t + row * K2P + ch * 8);
            }
        }
    }
    __syncthreads();

    // ---- GEMM2
    f32x4 acc2[2][4];
#pragma unroll
    for (int m = 0; m < 2; ++m)
#pragma unroll
        for (int j = 0; j < 4; ++j) acc2[m][j] = (f32x4){0.f, 0.f, 0.f, 0.f};
#pragma unroll
    for (int ks = 0; ks < 4; ++ks) {
        const int kb = ks * 32 + lk * 8;
        bf16x8 a[2];
#pragma unroll
        for (int m = 0; m < 2; ++m)
            a[m] = *reinterpret_cast<const bf16x8*>(&sm.g2.h1[wrow + m * 16 + l15][kb]);
#pragma unroll
        for (int j = 0; j < 4; ++j) {
            const int nf = nb + j;
            if (nf < 7) {
                const bf16x8 b = *reinterpret_cast<const bf16x8*>(
                    &sm.g2.u.w2s[nf * 16 + l15][kb]);
#pragma unroll
                for (int m = 0; m < 2; ++m)
                    acc2[m][j] = __builtin_amdgcn_mfma_f32_16x16x32_bf16(
                        a[m], b, acc2[m][j], 0, 0, 0);
            }
        }
    }
    __syncthreads();   // w2s reads done before h2 overwrites it

    // ---- h2 = relu(acc2+b2)
    {
        float bias[4];
#pragma unroll
        for (int j = 0; j < 4; ++j) {
            const int c = (nb + j) * 16 + l15;
            bias[j] = (nb + j < 7 && c < 100) ? b2[c] : 0.f;
        }
#pragma unroll
        for (int j = 0; j < 4; ++j) {
            const int nf = nb + j, col = nf * 16 + l15;
            if (nf < 7 && col < 100)
#pragma unroll
                for (int m = 0; m < 2; ++m)
#pragma unroll
                    for (int q = 0; q < 4; ++q)
                        sm.g2.u.h2[wrow + m * 16 + lk * 4 + q][col] =
                            f2bf(fmaxf(acc2[m][j][q] + bias[j], 0.f));
        }
        if (wv_n == 1) {
            for (int f = lane; f < 32 * 14; f += 64) {
                const int r = wrow + f / 14, c = 100 + (f % 14) * 2;
                *reinterpret_cast<unsigned int*>(&sm.g2.u.h2[r][c]) = 0u;
            }
        }
    }
    __syncthreads();

    // ---- GEMM3: M-split across wv_n (wave does m-frag = wv_n); nt stores
    {
        const int m = wv_n;
        f32x4 acc3 = (f32x4){0.f, 0.f, 0.f, 0.f};
#pragma unroll
        for (int ks = 0; ks < 4; ++ks) {
            const int kb = ks * 32 + lk * 8;
            const bf16x8 b = *reinterpret_cast<const bf16x8*>(w3t + l15 * K2P + kb);
            const bf16x8 a = *reinterpret_cast<const bf16x8*>(
                &sm.g2.u.h2[wrow + m * 16 + l15][kb]);
            acc3 = __builtin_amdgcn_mfma_f32_16x16x32_bf16(a, b, acc3, 0, 0, 0);
        }
        if (l15 < 10) {
            const float bb = b3[l15];
#pragma unroll
            for (int q = 0; q < 4; ++q) {
                const size_t row = b0 + wrow + m * 16 + lk * 4 + q;
                __builtin_nontemporal_store(acc3[q] + bb, &out[row * 10 + l15]);
            }
        }
    }
}

extern "C" void kernel_launch(void* const* d_in, const int* in_sizes, int n_in,
                              void* d_out, int out_size, void* d_ws, size_t ws_size,
                              hipStream_t stream) {
    const float* x      = (const float*)d_in[0];
    const float* w_conv = (const float*)d_in[1];
    const float* W1     = (const float*)d_in[2];
    const float* b1     = (const float*)d_in[3];
    const float* W2     = (const float*)d_in[4];
    const float* b2     = (const float*)d_in[5];
    const float* W3     = (const float*)d_in[6];
    const float* b3     = (const float*)d_in[7];
    float* out = (float*)d_out;
    unsigned short* ws = (unsigned short*)d_ws;

    const int total = 32 * KP1 + NP * K2P + 16 * K2P;   // 43008
    build_weights<<<(total + 255) / 256, 256, 0, stream>>>(w_conv, W1, W2, W3, ws);
    fused<<<32768 / BM, NT, 0, stream>>>(x, ws, b1, b2, b3, out);
}

// Round 15
// 32.981 us; speedup vs baseline: 1.0599x; 1.0599x over previous
//
#include <hip/hip_runtime.h>

// R15: R13 + three trims.
//   (1) nt-x reverted (R14 regression); GEMM3 M-split + nt-store kept.
//   (2) NPB=112: no junk weff rows; wv6/7's second B-gload duplicates rows
//       96-111 (L1/L2 hits) purely for vmcnt uniformity.
//   (3) W2 async-staged (T14): global->reg issued at K-loop exit (vmcnt=0),
//       pinned; lands under epilogue barrier + h1 writes; reg->LDS after sync.
//   Floor model: ~650 KB/CU vector bytes @ ~10B/cy/CU => ~26.5us fused.

typedef __attribute__((ext_vector_type(8))) short bf16x8;
typedef __attribute__((ext_vector_type(4))) float f32x4;

#define KP1 832
#define NP  112
#define K2P 128
#define BM  128
#define NT  512

#define W2T_OFF (NP * KP1)              // 93184
#define W3T_OFF (W2T_OFF + NP * K2P)    // 107520

#define SBAR0 __builtin_amdgcn_sched_barrier(0)
#define BAR   __builtin_amdgcn_s_barrier()
#define WAITV(N) asm volatile("s_waitcnt vmcnt(" #N ")" ::: "memory")
#define WAITL    asm volatile("s_waitcnt lgkmcnt(0)" ::: "memory")

__device__ __forceinline__ unsigned short f2bf(float f) {
    unsigned int u = __float_as_uint(f);
    u += 0x7FFFu + ((u >> 16) & 1u);    // RNE
    return (unsigned short)(u >> 16);
}

__device__ __forceinline__ unsigned int pkbf(float a, float b) {
    unsigned int r;
    asm("v_cvt_pk_bf16_f32 %0, %1, %2" : "=v"(r) : "v"(a), "v"(b));
    return r;
}

__device__ __forceinline__ void gload_lds16(const void* g, void* l) {
    __builtin_amdgcn_global_load_lds(
        (const __attribute__((address_space(1))) unsigned int*)g,
        (__attribute__((address_space(3))) unsigned int*)l, 16, 0, 0);
}

// ---------------- Kernel A: weights -> bf16, transposed, padded (112 rows)
__global__ void build_weights(const float* __restrict__ w_conv,
                              const float* __restrict__ W1,
                              const float* __restrict__ W2,
                              const float* __restrict__ W3,
                              unsigned short* __restrict__ ws) {
    const int idx = blockIdx.x * 256 + threadIdx.x;
    const int WEFF_T = 28 * KP1;                 // 28 j-quads = 112 rows
    if (idx < WEFF_T) {
        const int j4 = idx / KP1, p = idx % KP1;
        const int j = j4 * 4;
        float a0 = 0.f, a1 = 0.f, a2 = 0.f, a3 = 0.f;
        if (p < 784 && j4 < 25) {
            const int y = p / 28, xx = p % 28;
#pragma unroll
            for (int ky = 0; ky < 3; ++ky) {
                const int py = y - ky;
                if (py < 0 || py >= 26) continue;
#pragma unroll
                for (int kx = 0; kx < 3; ++kx) {
                    const int px = xx - kx;
                    if (px < 0 || px >= 26) continue;
                    const float wc = w_conv[ky * 3 + kx];
                    const float4 w = *reinterpret_cast<const float4*>(
                        W1 + (size_t)(py * 26 + px) * 100 + j);
                    a0 = fmaf(wc, w.x, a0); a1 = fmaf(wc, w.y, a1);
                    a2 = fmaf(wc, w.z, a2); a3 = fmaf(wc, w.w, a3);
                }
            }
        }
        ws[(size_t)(j + 0) * KP1 + p] = f2bf(a0);
        ws[(size_t)(j + 1) * KP1 + p] = f2bf(a1);
        ws[(size_t)(j + 2) * KP1 + p] = f2bf(a2);
        ws[(size_t)(j + 3) * KP1 + p] = f2bf(a3);
    } else if (idx < WEFF_T + NP * K2P) {
        const int r = idx - WEFF_T;
        const int col = r / K2P, k = r % K2P;
        float v = (col < 100 && k < 100) ? W2[k * 100 + col] : 0.f;
        ws[W2T_OFF + r] = f2bf(v);
    } else if (idx < WEFF_T + NP * K2P + 16 * K2P) {
        const int r = idx - WEFF_T - NP * K2P;
        const int col = r / K2P, k = r % K2P;
        float v = (col < 10 && k < 100) ? W3[k * 10 + col] : 0.f;
        ws[W3T_OFF + r] = f2bf(v);
    }
}

// ---------------- Kernel B: fused
union SMem {
    struct {
        unsigned short xs[2][BM][72];    // 36864 B (bf16, 2-way banks)
        unsigned short bs[2][128][64];   // 32768 B (16 groups; 14 real + 2 dup)
    } g1;                                 // 69632 B
    struct {
        unsigned short h1[BM][136];      // 34816 B
        union {
            unsigned short w2s[NP][136]; // 30464 B (dead before h2 written)
            unsigned short h2[BM][136];  // 34816 B
        } u;
    } g2;                                 // 69632 B
};

__global__ __launch_bounds__(NT, 2)
void fused(const float* __restrict__ x,
           const unsigned short* __restrict__ wst,
           const float* __restrict__ b1,
           const float* __restrict__ b2,
           const float* __restrict__ b3,
           float* __restrict__ out) {
    __shared__ SMem sm;
    const int tid  = threadIdx.x;
    const int lane = tid & 63;
    const int wv   = tid >> 6;        // 0..7
    const int wv_m = wv >> 1;         // 0..3 -> rows wv_m*32 (2 m-frags)
    const int wv_n = wv & 1;          // 0..1 -> frags wv_n*4..(+3|+2)
    const int l15  = lane & 15;
    const int lk   = lane >> 4;       // 0..3
    const int wrow = wv_m * 32;
    const int nb   = wv_n * 4;
    const size_t b0 = (size_t)blockIdx.x * BM;

    const unsigned short* weff = wst;
    const unsigned short* w2t  = wst + W2T_OFF;
    const unsigned short* w3t  = wst + W3T_OFF;

    // x staging map: idx=q*512+tid -> row=idx>>4 (xrow+q*32), chunk=idx&15
    const int xrow = tid >> 4;
    const int xch  = tid & 15;
    const float* xbase = x + (b0 + xrow) * 784 + xch * 4;

    f32x4 acc[2][4];
#pragma unroll
    for (int m = 0; m < 2; ++m)
#pragma unroll
        for (int j = 0; j < 4; ++j) acc[m][j] = (f32x4){0.f, 0.f, 0.f, 0.f};

    float4 xv[4];
    auto issueX = [&](int kt) {
#pragma unroll
        for (int q = 0; q < 4; ++q) {
            if (kt < 12 || xch < 4)   // stage 12: cols>=784 are pad
                xv[q] = *reinterpret_cast<const float4*>(xbase + (size_t)q * 32 * 784 + kt * 64);
            else
                xv[q] = (float4){0.f, 0.f, 0.f, 0.f};
        }
    };
    auto writeX = [&](int buf) {
        char* xp = (char*)&sm.g1.xs[buf][0][0];
#pragma unroll
        for (int q = 0; q < 4; ++q) {
            const uint2 w = {pkbf(xv[q].x, xv[q].y), pkbf(xv[q].z, xv[q].w)};
            *reinterpret_cast<uint2*>(xp + (xrow + q * 32) * 144 + xch * 8) = w;
        }
    };
    // 2 gloads/wave (vmcnt-uniform). Dest groups wv, wv+8; source groups
    // clamp to <14: wv6/7's 2nd gload re-reads rows 96..111 (L1/L2-hot dup).
    auto issueB = [&](int kt, int buf) {
#pragma unroll
        for (int q = 0; q < 2; ++q) {
            const int g  = wv + 8 * q;            // dest group 0..15
            const int gs = (g < 14) ? g : g - 2;  // source group 0..13
            const int rg = gs * 8 + (lane >> 3);
            const int ch = (lane & 7) ^ (lane >> 3);       // inverse swizzle
            gload_lds16((const char*)weff + (size_t)rg * KP1 * 2 + kt * 128 + ch * 16,
                        &sm.g1.bs[buf][g * 8][0]);
        }
    };
    auto computeStage = [&](int buf) {
        const char* xp = (const char*)&sm.g1.xs[buf][0][0];
        const char* bp = (const char*)&sm.g1.bs[buf][0][0];
#pragma unroll
        for (int kh = 0; kh < 2; ++kh) {
            bf16x8 a[2];
#pragma unroll
            for (int m = 0; m < 2; ++m)
                a[m] = *reinterpret_cast<const bf16x8*>(
                    xp + (wrow + m * 16 + l15) * 144 + kh * 64 + lk * 16);
#pragma unroll
            for (int j = 0; j < 4; ++j) {
                const int nf = nb + j;
                if (nf < 7) {
                    const int rn = nf * 16 + l15;
                    const bf16x8 b = *reinterpret_cast<const bf16x8*>(
                        bp + rn * 128 + ((kh * 64 + lk * 16) ^ ((rn & 7) << 4)));
#pragma unroll
                    for (int m = 0; m < 2; ++m)
                        acc[m][j] = __builtin_amdgcn_mfma_f32_16x16x32_bf16(
                            a[m], b, acc[m][j], 0, 0, 0);
                }
            }
        }
    };

    // ---- GEMM1 prologue
    issueX(0); SBAR0;
    issueB(0, 0); SBAR0;
    WAITV(2); SBAR0;              // x(0) landed (B(0) in flight)
    writeX(0); SBAR0;
    issueX(1); SBAR0;             // outstanding: B(0)2 + x(1)4
    WAITV(4);                     // B(0) landed
    WAITL; BAR;

    // ---- GEMM1: 13 stages; entering t: xs/bs[t&1] ready, x(t+1) in flight
#pragma unroll
    for (int t = 0; t < 13; ++t) {
        if (t < 12) { issueB(t + 1, (t + 1) & 1); SBAR0; }   // buf retired at barrier(t-1)
        computeStage(t & 1);
        if (t == 12) break;
        WAITV(2); SBAR0;          // x(t+1) landed (B(t+1) in flight)
        writeX((t + 1) & 1); SBAR0;
        if (t < 11) { issueX(t + 2); SBAR0; WAITV(4); }      // B(t+1) landed
        else        { WAITV(0); }                             // drain B(12)
        WAITL; BAR;
    }

    // ---- T14: issue W2 global->reg NOW (vmcnt==0 here); lands under the
    //      barrier + h1 ds_writes; written to LDS after __syncthreads.
    bf16x8 w2r[4];
#pragma unroll
    for (int q = 0; q < 4; ++q) {
        const int idx = q * NT + tid;
        if (idx < 1792)
            w2r[q] = *reinterpret_cast<const bf16x8*>(
                w2t + (idx >> 4) * K2P + (idx & 15) * 8);
    }
    SBAR0;             // pin issues before the barrier (don't sink past sync)
    __syncthreads();   // all g1 reads done -> g2 alias safe

    // ---- h1 = relu(acc+b1); h1 k-pad; write staged W2 -> LDS
    {
        float bias[4];
#pragma unroll
        for (int j = 0; j < 4; ++j) {
            const int c = (nb + j) * 16 + l15;
            bias[j] = (nb + j < 7 && c < 100) ? b1[c] : 0.f;
        }
#pragma unroll
        for (int j = 0; j < 4; ++j) {
            const int nf = nb + j, col = nf * 16 + l15;
            if (nf < 7 && col < 100)
#pragma unroll
                for (int m = 0; m < 2; ++m)
#pragma unroll
                    for (int q = 0; q < 4; ++q)
                        sm.g2.h1[wrow + m * 16 + lk * 4 + q][col] =
                            f2bf(fmaxf(acc[m][j][q] + bias[j], 0.f));
        }
        if (wv_n == 1) {   // zero h1 pad cols 100..127 for rows wrow..wrow+31
            for (int f = lane; f < 32 * 14; f += 64) {
                const int r = wrow + f / 14, c = 100 + (f % 14) * 2;
                *reinterpret_cast<unsigned int*>(&sm.g2.h1[r][c]) = 0u;
            }
        }
#pragma unroll
        for (int q = 0; q < 4; ++q) {   // w2s[112][136] <- staged regs
            const int idx = q * NT + tid;
            if (idx < 1792)
                *reinterpret_cast<bf16x8*>(&sm.g2.u.w2s[idx >> 4][(idx & 15) * 8]) = w2r[q];
        }
    }
    __syncthreads();

    // ---- GEMM2
    f32x4 acc2[2][4];
#pragma unroll
    for (int m = 0; m < 2; ++m)
#pragma unroll
        for (int j = 0; j < 4; ++j) acc2[m][j] = (f32x4){0.f, 0.f, 0.f, 0.f};
#pragma unroll
    for (int ks = 0; ks < 4; ++ks) {
        const int kb = ks * 32 + lk * 8;
        bf16x8 a[2];
#pragma unroll
        for (int m = 0; m < 2; ++m)
            a[m] = *reinterpret_cast<const bf16x8*>(&sm.g2.h1[wrow + m * 16 + l15][kb]);
#pragma unroll
        for (int j = 0; j < 4; ++j) {
            const int nf = nb + j;
            if (nf < 7) {
                const bf16x8 b = *reinterpret_cast<const bf16x8*>(
                    &sm.g2.u.w2s[nf * 16 + l15][kb]);
#pragma unroll
                for (int m = 0; m < 2; ++m)
                    acc2[m][j] = __builtin_amdgcn_mfma_f32_16x16x32_bf16(
                        a[m], b, acc2[m][j], 0, 0, 0);
            }
        }
    }
    __syncthreads();   // w2s reads done before h2 overwrites it

    // ---- h2 = relu(acc2+b2)
    {
        float bias[4];
#pragma unroll
        for (int j = 0; j < 4; ++j) {
            const int c = (nb + j) * 16 + l15;
            bias[j] = (nb + j < 7 && c < 100) ? b2[c] : 0.f;
        }
#pragma unroll
        for (int j = 0; j < 4; ++j) {
            const int nf = nb + j, col = nf * 16 + l15;
            if (nf < 7 && col < 100)
#pragma unroll
                for (int m = 0; m < 2; ++m)
#pragma unroll
                    for (int q = 0; q < 4; ++q)
                        sm.g2.u.h2[wrow + m * 16 + lk * 4 + q][col] =
                            f2bf(fmaxf(acc2[m][j][q] + bias[j], 0.f));
        }
        if (wv_n == 1) {
            for (int f = lane; f < 32 * 14; f += 64) {
                const int r = wrow + f / 14, c = 100 + (f % 14) * 2;
                *reinterpret_cast<unsigned int*>(&sm.g2.u.h2[r][c]) = 0u;
            }
        }
    }
    __syncthreads();

    // ---- GEMM3: M-split across wv_n; nt stores
    {
        const int m = wv_n;
        f32x4 acc3 = (f32x4){0.f, 0.f, 0.f, 0.f};
#pragma unroll
        for (int ks = 0; ks < 4; ++ks) {
            const int kb = ks * 32 + lk * 8;
            const bf16x8 b = *reinterpret_cast<const bf16x8*>(w3t + l15 * K2P + kb);
            const bf16x8 a = *reinterpret_cast<const bf16x8*>(
                &sm.g2.u.h2[wrow + m * 16 + l15][kb]);
            acc3 = __builtin_amdgcn_mfma_f32_16x16x32_bf16(a, b, acc3, 0, 0, 0);
        }
        if (l15 < 10) {
            const float bb = b3[l15];
#pragma unroll
            for (int q = 0; q < 4; ++q) {
                const size_t row = b0 + wrow + m * 16 + lk * 4 + q;
                __builtin_nontemporal_store(acc3[q] + bb, &out[row * 10 + l15]);
            }
        }
    }
}

extern "C" void kernel_launch(void* const* d_in, const int* in_sizes, int n_in,
                              void* d_out, int out_size, void* d_ws, size_t ws_size,
                              hipStream_t stream) {
    const float* x      = (const float*)d_in[0];
    const float* w_conv = (const float*)d_in[1];
    const float* W1     = (const float*)d_in[2];
    const float* b1     = (const float*)d_in[3];
    const float* W2     = (const float*)d_in[4];
    const float* b2     = (const float*)d_in[5];
    const float* W3     = (const float*)d_in[6];
    const float* b3     = (const float*)d_in[7];
    float* out = (float*)d_out;
    unsigned short* ws = (unsigned short*)d_ws;

    const int total = 28 * KP1 + NP * K2P + 16 * K2P;   // 39680
    build_weights<<<(total + 255) / 256, 256, 0, stream>>>(w_conv, W1, W2, W3, ws);
    fused<<<32768 / BM, NT, 0, stream>>>(x, ws, b1, b2, b3, out);
}